// Round 3
// baseline (197.286 us; speedup 1.0000x reference)
//
#include <hip/hip_runtime.h>
#include <cstdint>

// NeuralRadiance via bf16 MFMA (16x16x32).
//   L1 (transposed): h1^T = W1^T @ x^T   -- b1 folded as x[k=19]=1.0
//   L2 (transposed): h2^T = W2^T @ h1^T  -- b2 via acc init
//   L3 (normal)    : h3   = h2  @ W3     -- b3 via acc init
// Fragment facts (HW-verified per guide):
//   A-frag: lane holds A[m=lane&15][k=quad*8+j], 8 bf16
//   B-frag: lane holds B[k=quad*8+j][n=lane&15], 8 bf16
//   C/D   : lane reg r holds D[m=quad*4+r][n=lane&15], 4 f32
// Round 3: HW v_cvt_pk_bf16_f32 (guarded), LDS arena reuse (24.6KB),
// XOR-swizzled conflict-free strides, register prefetch of next tile,
// grid=1024 -> exactly 8 tiles/wave, __launch_bounds__(256,4).

typedef short  bf16x8 __attribute__((ext_vector_type(8)));
typedef float  f32x4  __attribute__((ext_vector_type(4)));

#define MFMA16(A, B, C) __builtin_amdgcn_mfma_f32_16x16x32_bf16((A), (B), (C), 0, 0, 0)

// RNE float->bf16 (manual fallback)
__device__ inline uint32_t f2b_u(float f) {
    union { float f; uint32_t u; } x; x.f = f;
    return (x.u + 0x7FFFu + ((x.u >> 16) & 1u)) >> 16;
}
__device__ inline short f2b(float f) { return (short)f2b_u(f); }

#if defined(__has_builtin)
#  if __has_builtin(__builtin_amdgcn_cvt_pk_bf16_f32)
#    define HAVE_PK_BF16 1
#  endif
#endif

// pack two f32 -> dword of 2 bf16 (lo = a, hi = b)
__device__ inline int pk(float a, float b) {
#ifdef HAVE_PK_BF16
    auto v = __builtin_amdgcn_cvt_pk_bf16_f32(a, b);   // dst.lo=cvt(a), dst.hi=cvt(b)
    int i; __builtin_memcpy(&i, &v, sizeof(i));
    return i;
#else
    return (int)(f2b_u(a) | (f2b_u(b) << 16));
#endif
}

__device__ inline void lds_fence() {
    __asm__ volatile("s_waitcnt lgkmcnt(0)" ::: "memory");
}

__global__ __launch_bounds__(256, 4) void nrad_mfma_kernel(
    const float* __restrict__ pos, const float* __restrict__ nrm,
    const float* __restrict__ emb,
    const float* __restrict__ W1, const float* __restrict__ b1,
    const float* __restrict__ W2, const float* __restrict__ b2,
    const float* __restrict__ W3, const float* __restrict__ b3,
    float* __restrict__ out, int ntiles)
{
    // One arena, two lifetimes:
    //  phase 1 (weights, consumed into regs): w1t@0 (4KB), w2t@4096 (8KB),
    //    w3t@12288 (384B), b2s@12672 (256B), b3s@12928 (16B)
    //  phase 2 (hot): xbuf = arena + wave*4096 (64 rows x 32 shorts),
    //    hbuf = arena + 16384 + wave*2048 (16 rows x 64 shorts)
    __shared__ alignas(16) char arena[24576];
    short* w1t = (short*)arena;             // [n][k], stride 32: k<19=W1, k==19=b1
    short* w2t = (short*)(arena + 4096);    // [n][k], stride 64
    short* w3t = (short*)(arena + 12288);   // [c][k], stride 64
    float* b2s = (float*)(arena + 12672);
    float* b3s = (float*)(arena + 12928);

    const int tid  = threadIdx.x;
    const int wave = tid >> 6;
    const int lane = tid & 63;
    const int q    = lane >> 4;
    const int nn   = lane & 15;

    // ---- one-time: stage transposed bf16 weights into LDS
    for (int e = tid; e < 64 * 32; e += 256) {
        int n = e >> 5, k = e & 31;
        float v = (k < 19) ? W1[k * 64 + n] : (k == 19 ? b1[n] : 0.0f);
        w1t[n * 32 + k] = f2b(v);
    }
    for (int e = tid; e < 4096; e += 256) {
        int k = e >> 6, n = e & 63;
        w2t[n * 64 + k] = f2b(W2[e]);
    }
    for (int e = tid; e < 192; e += 256) {
        int k = e / 3, c = e - k * 3;
        w3t[c * 64 + k] = f2b(W3[e]);
    }
    for (int e = tid; e < 64; e += 256) b2s[e] = b2[e];
    if (tid < 4) b3s[tid] = (tid < 3) ? b3[tid] : 0.0f;
    __syncthreads();

    // ---- per-lane register fragments (persistent across tiles)
    bf16x8 w1f[4], w2f[4][2], w3f[2];
    #pragma unroll
    for (int t = 0; t < 4; ++t)
        w1f[t] = *(const bf16x8*)(w1t + (t * 16 + nn) * 32 + q * 8);
    #pragma unroll
    for (int t = 0; t < 4; ++t)
        #pragma unroll
        for (int ks = 0; ks < 2; ++ks)
            w2f[t][ks] = *(const bf16x8*)(w2t + (t * 16 + nn) * 64 + ks * 32 + q * 8);
    {
        int c3 = (nn < 3) ? nn : 0;
        w3f[0] = *(const bf16x8*)(w3t + c3 * 64 + q * 8);
        w3f[1] = *(const bf16x8*)(w3t + c3 * 64 + 32 + q * 8);
    }
    float b2r[16];
    #pragma unroll
    for (int t = 0; t < 4; ++t)
        #pragma unroll
        for (int r = 0; r < 4; ++r)
            b2r[t * 4 + r] = b2s[t * 16 + q * 4 + r];
    const float b3r = (nn < 3) ? b3s[nn] : 0.0f;
    __syncthreads();   // weights fully consumed; arena is now reusable by all waves

    short* xw = (short*)(arena + wave * 4096);           // row stride 32 shorts
    short* hw = (short*)(arena + 16384 + wave * 2048);   // row stride 64 shorts

    // ---- precomputed swizzled offsets (shorts)
    // xbuf write: lane's own row L=lane; phys chunk = c ^ ((L>>1)&3), 4 chunks of 8 shorts
    const int sxw = (lane >> 1) & 3;
    int xwo[4];
    #pragma unroll
    for (int c = 0; c < 4; ++c) xwo[c] = lane * 32 + 8 * (c ^ sxw);
    // xbuf read: row r = sub*16+nn, chunk q -> phys q ^ ((nn>>1)&3)
    const int xro = nn * 32 + 8 * (q ^ ((nn >> 1) & 3));   // + sub*512
    // hbuf write: row nn, t: chunk 2t+(q>>1) ^ (nn&7), half q&1
    const int sh = nn & 7;
    int hwo[4];
    #pragma unroll
    for (int t = 0; t < 4; ++t)
        hwo[t] = nn * 64 + 8 * ((2 * t + (q >> 1)) ^ sh) + 4 * (q & 1);
    // hbuf read: row nn, frag ks: chunk 4ks+q ^ (nn&7)
    const int hro0 = nn * 64 + 8 * ((q) ^ sh);
    const int hro1 = nn * 64 + 8 * ((4 + q) ^ sh);

    const int wave_gid = blockIdx.x * 4 + wave;
    const int nwaves   = gridDim.x * 4;
    const float4* emb4 = (const float4*)emb;

    // ---- prefetch first tile's point
    int tile = wave_gid;
    float p0=0, p1=0, p2=0, n0=0, n1=0, n2=0;
    float4 f0{}, f1{}, f2{}, f3{};
    if (tile < ntiles) {
        int i = tile * 64 + lane;
        const float* pp = pos + 3 * i;
        const float* np = nrm + 3 * i;
        p0 = pp[0]; p1 = pp[1]; p2 = pp[2];
        n0 = np[0]; n1 = np[1]; n2 = np[2];
        int s0 = (int)(p0 * 8.0f), s1 = (int)(p1 * 8.0f), s2 = (int)(p2 * 8.0f);
        uint32_t h = ((uint32_t)s0 * 73856093u) ^ ((uint32_t)s1 * 19349663u) ^
                     ((uint32_t)s2 * 83492791u);
        uint32_t idx = h & 32767u;
        f0 = emb4[idx*4+0]; f1 = emb4[idx*4+1]; f2 = emb4[idx*4+2]; f3 = emb4[idx*4+3];
    }

    for (; tile < ntiles; tile += nwaves) {
        const int base = tile * 64;

        // ---- pack current point into xbuf (swizzled chunks)
        int4 A = make_int4(pk(f0.x, f0.y), pk(f0.z, f0.w), pk(f1.x, f1.y), pk(f1.z, f1.w));
        int4 B = make_int4(pk(f2.x, f2.y), pk(f2.z, f2.w), pk(f3.x, f3.y), pk(f3.z, f3.w));
        int4 C = make_int4(pk(n0, n1), pk(n2, 1.0f), 0, 0);  // k=19 -> 1.0 (bias row)
        int4 D = make_int4(0, 0, 0, 0);
        *(int4*)(xw + xwo[0]) = A;
        *(int4*)(xw + xwo[1]) = B;
        *(int4*)(xw + xwo[2]) = C;
        *(int4*)(xw + xwo[3]) = D;

        // ---- issue next tile's global loads (hidden under the 4 sub-tiles)
        {
            int nt = tile + nwaves;
            int lt = (nt < ntiles) ? nt : tile;   // wave-uniform; harmless reload at end
            int i = lt * 64 + lane;
            const float* pp = pos + 3 * i;
            const float* np = nrm + 3 * i;
            p0 = pp[0]; p1 = pp[1]; p2 = pp[2];
            n0 = np[0]; n1 = np[1]; n2 = np[2];
            int s0 = (int)(p0 * 8.0f), s1 = (int)(p1 * 8.0f), s2 = (int)(p2 * 8.0f);
            uint32_t h = ((uint32_t)s0 * 73856093u) ^ ((uint32_t)s1 * 19349663u) ^
                         ((uint32_t)s2 * 83492791u);
            uint32_t idx = h & 32767u;
            f0 = emb4[idx*4+0]; f1 = emb4[idx*4+1];
            f2 = emb4[idx*4+2]; f3 = emb4[idx*4+3];
        }

        lds_fence();   // x writes visible to this wave's reads

        #pragma unroll
        for (int sub = 0; sub < 4; ++sub) {
            // ---- L1: h1^T = W1^T @ x^T
            bf16x8 xf = *(const bf16x8*)(xw + sub * 512 + xro);
            f32x4 acc1[4];
            #pragma unroll
            for (int t = 0; t < 4; ++t) {
                f32x4 z = {0.0f, 0.0f, 0.0f, 0.0f};
                acc1[t] = MFMA16(w1f[t], xf, z);
            }
            #pragma unroll
            for (int t = 0; t < 4; ++t) {
                float a0 = fmaxf(acc1[t][0], 0.0f), a1 = fmaxf(acc1[t][1], 0.0f);
                float a2 = fmaxf(acc1[t][2], 0.0f), a3 = fmaxf(acc1[t][3], 0.0f);
                *(int2*)(hw + hwo[t]) = make_int2(pk(a0, a1), pk(a2, a3));
            }
            lds_fence();

            // ---- L2: h2^T = W2^T @ h1^T
            bf16x8 h1f0 = *(const bf16x8*)(hw + hro0);
            bf16x8 h1f1 = *(const bf16x8*)(hw + hro1);
            f32x4 acc2[4];
            #pragma unroll
            for (int t = 0; t < 4; ++t) {
                f32x4 c2 = {b2r[t * 4 + 0], b2r[t * 4 + 1], b2r[t * 4 + 2], b2r[t * 4 + 3]};
                c2 = MFMA16(w2f[t][0], h1f0, c2);
                acc2[t] = MFMA16(w2f[t][1], h1f1, c2);
            }
            // h2 overwrites h1 rows; write data depends on the reads -> in-order safe
            #pragma unroll
            for (int t = 0; t < 4; ++t) {
                float a0 = fmaxf(acc2[t][0], 0.0f), a1 = fmaxf(acc2[t][1], 0.0f);
                float a2 = fmaxf(acc2[t][2], 0.0f), a3 = fmaxf(acc2[t][3], 0.0f);
                *(int2*)(hw + hwo[t]) = make_int2(pk(a0, a1), pk(a2, a3));
            }
            lds_fence();

            // ---- L3: h3 = h2 @ W3
            bf16x8 h2f0 = *(const bf16x8*)(hw + hro0);
            bf16x8 h2f1 = *(const bf16x8*)(hw + hro1);
            f32x4 acc3 = {b3r, b3r, b3r, b3r};
            acc3 = MFMA16(h2f0, w3f[0], acc3);
            acc3 = MFMA16(h2f1, w3f[1], acc3);
            lds_fence();   // h2 reads drained before next sub's h1 writes (WAR)

            // ---- sigmoid + store: lane (q, nn<3), reg r -> out[pt][nn]
            float o0 = 1.0f / (1.0f + __expf(-acc3[0]));
            float o1 = 1.0f / (1.0f + __expf(-acc3[1]));
            float o2 = 1.0f / (1.0f + __expf(-acc3[2]));
            float o3 = 1.0f / (1.0f + __expf(-acc3[3]));
            if (nn < 3) {
                int p = base + sub * 16 + q * 4;
                out[(p + 0) * 3 + nn] = o0;
                out[(p + 1) * 3 + nn] = o1;
                out[(p + 2) * 3 + nn] = o2;
                out[(p + 3) * 3 + nn] = o3;
            }
        }
        lds_fence();   // xbuf reads drained before next tile's staging writes (WAR)
    }
}

extern "C" void kernel_launch(void* const* d_in, const int* in_sizes, int n_in,
                              void* d_out, int out_size, void* d_ws, size_t ws_size,
                              hipStream_t stream) {
    const float* pos = (const float*)d_in[0];
    const float* nrm = (const float*)d_in[1];
    const float* emb = (const float*)d_in[2];
    const float* W1  = (const float*)d_in[3];
    const float* b1  = (const float*)d_in[4];
    const float* W2  = (const float*)d_in[5];
    const float* b2  = (const float*)d_in[6];
    const float* W3  = (const float*)d_in[7];
    const float* b3  = (const float*)d_in[8];
    float* out = (float*)d_out;

    int n = in_sizes[0] / 3;      // 2,097,152
    int ntiles = n / 64;          // 32768
    int grid = 1024;              // 4096 waves -> exactly 8 tiles each; 4 blocks/CU
    nrad_mfma_kernel<<<grid, 256, 0, stream>>>(pos, nrm, emb, W1, b1, W2, b2,
                                               W3, b3, out, ntiles);
}

// Round 4
// 165.765 us; speedup vs baseline: 1.1902x; 1.1902x over previous
//
#include <hip/hip_runtime.h>
#include <cstdint>

// NeuralRadiance via bf16 MFMA (16x16x32).
//   L1 (transposed): h1^T = W1^T @ x^T   -- b1 folded as x[k=19]=1.0
//   L2 (transposed): h2^T = W2^T @ h1^T  -- b2 via acc init
//   L3 (normal)    : h3   = h2  @ W3     -- b3 via acc init
// Fragment facts (HW-verified per guide):
//   A-frag: lane holds A[m=lane&15][k=quad*8+j], 8 bf16
//   B-frag: lane holds B[k=quad*8+j][n=lane&15], 8 bf16
//   C/D   : lane reg r holds D[m=quad*4+r][n=lane&15], 4 f32
// Round 4: r2 padded strides (already at bank floor), HW pk cvt, rcp sigmoid,
// compile-time-only LDS fences (DS pipe is in-order per wave -> no HW drain
// needed for intra-wave cross-lane round-trips), no prefetch (reg pressure),
// launch_bounds(256,3) so nothing spills.

typedef short  bf16x8 __attribute__((ext_vector_type(8)));
typedef float  f32x4  __attribute__((ext_vector_type(4)));

#define MFMA16(A, B, C) __builtin_amdgcn_mfma_f32_16x16x32_bf16((A), (B), (C), 0, 0, 0)

// RNE float->bf16 (manual fallback)
__device__ inline uint32_t f2b_u(float f) {
    union { float f; uint32_t u; } x; x.f = f;
    return (x.u + 0x7FFFu + ((x.u >> 16) & 1u)) >> 16;
}
__device__ inline short f2b(float f) { return (short)f2b_u(f); }

#if defined(__has_builtin)
#  if __has_builtin(__builtin_amdgcn_cvt_pk_bf16_f32)
#    define HAVE_PK_BF16 1
#  endif
#endif

// pack two f32 -> dword of 2 bf16 (lo = a, hi = b)
__device__ inline int pk(float a, float b) {
#ifdef HAVE_PK_BF16
    auto v = __builtin_amdgcn_cvt_pk_bf16_f32(a, b);
    int i; __builtin_memcpy(&i, &v, sizeof(i));
    return i;
#else
    return (int)(f2b_u(a) | (f2b_u(b) << 16));
#endif
}

// Compile-time ordering only: DS pipe services a wave's LDS ops in issue
// order, so cross-lane write->read within one wave needs no HW waitcnt
// (the compiler still inserts precise lgkmcnt for the read's data use).
__device__ inline void cfence() { __asm__ volatile("" ::: "memory"); }

__device__ inline float sigmoid_fast(float x) {
    float e = __expf(-x);                       // v_mul + v_exp
    return __builtin_amdgcn_rcpf(1.0f + e);     // v_add + v_rcp (~1 ulp, fine @1e-2 thr)
}

#define XS 40   // xbuf row stride (shorts) = 20 dwords: b128 pattern at bank floor
#define HS 72   // hbuf row stride (shorts) = 36 dwords: b64/b128 at bank floor

__global__ __launch_bounds__(256, 3) void nrad_mfma_kernel(
    const float* __restrict__ pos, const float* __restrict__ nrm,
    const float* __restrict__ emb,
    const float* __restrict__ W1, const float* __restrict__ b1,
    const float* __restrict__ W2, const float* __restrict__ b2,
    const float* __restrict__ W3, const float* __restrict__ b3,
    float* __restrict__ out, int ntiles)
{
    // Arena, two lifetimes (barrier-separated):
    //  phase 1: w1t@0 (4KB) w2t@4096 (8KB) w3t@12288 (384B) b2s@12672 b3s@12928
    //  phase 2: xbuf = arena + wave*5120 (64 rows x XS shorts)
    //           hbuf = arena + 20480 + wave*2304 (16 rows x HS shorts)
    __shared__ alignas(16) char arena[29696];
    short* w1t = (short*)arena;             // [n][k] stride 32: k<19=W1, k==19=b1
    short* w2t = (short*)(arena + 4096);    // [n][k] stride 64
    short* w3t = (short*)(arena + 12288);   // [c][k] stride 64
    float* b2s = (float*)(arena + 12672);
    float* b3s = (float*)(arena + 12928);

    const int tid  = threadIdx.x;
    const int wave = tid >> 6;
    const int lane = tid & 63;
    const int q    = lane >> 4;
    const int nn   = lane & 15;

    // ---- one-time: stage transposed bf16 weights into LDS
    for (int e = tid; e < 64 * 32; e += 256) {
        int n = e >> 5, k = e & 31;
        float v = (k < 19) ? W1[k * 64 + n] : (k == 19 ? b1[n] : 0.0f);
        w1t[n * 32 + k] = f2b(v);
    }
    for (int e = tid; e < 4096; e += 256) {
        int k = e >> 6, n = e & 63;
        w2t[n * 64 + k] = f2b(W2[e]);
    }
    for (int e = tid; e < 192; e += 256) {
        int k = e / 3, c = e - k * 3;
        w3t[c * 64 + k] = f2b(W3[e]);
    }
    for (int e = tid; e < 64; e += 256) b2s[e] = b2[e];
    if (tid < 4) b3s[tid] = (tid < 3) ? b3[tid] : 0.0f;
    __syncthreads();

    // ---- per-lane register fragments (persistent; arena dies after barrier,
    // so these CANNOT be remat'd -- they stay live in VGPRs)
    bf16x8 w1f[4], w2f[4][2], w3f[2];
    #pragma unroll
    for (int t = 0; t < 4; ++t)
        w1f[t] = *(const bf16x8*)(w1t + (t * 16 + nn) * 32 + q * 8);
    #pragma unroll
    for (int t = 0; t < 4; ++t)
        #pragma unroll
        for (int ks = 0; ks < 2; ++ks)
            w2f[t][ks] = *(const bf16x8*)(w2t + (t * 16 + nn) * 64 + ks * 32 + q * 8);
    {
        int c3 = (nn < 3) ? nn : 0;
        w3f[0] = *(const bf16x8*)(w3t + c3 * 64 + q * 8);
        w3f[1] = *(const bf16x8*)(w3t + c3 * 64 + 32 + q * 8);
    }
    f32x4 b2rv[4];
    #pragma unroll
    for (int t = 0; t < 4; ++t)
        b2rv[t] = *(const f32x4*)(b2s + t * 16 + q * 4);
    const float b3r = (nn < 3) ? b3s[nn] : 0.0f;
    __syncthreads();   // weights consumed into regs; arena now reusable

    short* xw = (short*)(arena + wave * 5120);            // row stride XS
    short* hw = (short*)(arena + 20480 + wave * 2304);    // row stride HS

    const int xro  = nn * XS + q * 8;       // + sub*16*XS : L1 B-frag read
    const int hro0 = nn * HS + q * 8;       // L2/L3 frag reads (+32 for hi half)
    const int oofs = q * 12 + nn;           // output: (q*4+r)*3+nn, r via +3*r

    const int wave_gid = blockIdx.x * 4 + wave;
    const int nwaves   = gridDim.x * 4;
    const float4* emb4 = (const float4*)emb;

    for (int tile = wave_gid; tile < ntiles; tile += nwaves) {
        const int base = tile * 64;
        const int i    = base + lane;

        // ---- load + hash + gather this lane's point
        const float* pp = pos + 3 * i;
        const float* np = nrm + 3 * i;
        float p0 = pp[0], p1 = pp[1], p2 = pp[2];
        float n0 = np[0], n1 = np[1], n2 = np[2];
        int s0 = (int)(p0 * 8.0f), s1 = (int)(p1 * 8.0f), s2 = (int)(p2 * 8.0f);
        uint32_t h = ((uint32_t)s0 * 73856093u) ^ ((uint32_t)s1 * 19349663u) ^
                     ((uint32_t)s2 * 83492791u);
        uint32_t idx = h & 32767u;
        float4 f0 = emb4[idx*4+0], f1 = emb4[idx*4+1];
        float4 f2 = emb4[idx*4+2], f3 = emb4[idx*4+3];

        // ---- pack into xbuf row = lane (k-major, 32 shorts + 8 pad)
        int4 A = make_int4(pk(f0.x, f0.y), pk(f0.z, f0.w), pk(f1.x, f1.y), pk(f1.z, f1.w));
        int4 B = make_int4(pk(f2.x, f2.y), pk(f2.z, f2.w), pk(f3.x, f3.y), pk(f3.z, f3.w));
        int4 C = make_int4(pk(n0, n1), pk(n2, 1.0f), 0, 0);  // k=19 -> 1.0 (bias row)
        int4 D = make_int4(0, 0, 0, 0);
        int4* xr = (int4*)(xw + lane * XS);
        xr[0] = A; xr[1] = B; xr[2] = C; xr[3] = D;
        cfence();

        const float* ob = out + (size_t)base * 3;

        #pragma unroll
        for (int sub = 0; sub < 4; ++sub) {
            // ---- L1: h1^T = W1^T @ x^T
            bf16x8 xf = *(const bf16x8*)(xw + sub * 16 * XS + xro);
            f32x4 acc1[4];
            #pragma unroll
            for (int t = 0; t < 4; ++t) {
                f32x4 z = {0.0f, 0.0f, 0.0f, 0.0f};
                acc1[t] = MFMA16(w1f[t], xf, z);
            }
            cfence();
            #pragma unroll
            for (int t = 0; t < 4; ++t) {
                float a0 = fmaxf(acc1[t][0], 0.0f), a1 = fmaxf(acc1[t][1], 0.0f);
                float a2 = fmaxf(acc1[t][2], 0.0f), a3 = fmaxf(acc1[t][3], 0.0f);
                *(int2*)(hw + nn * HS + t * 16 + q * 4) = make_int2(pk(a0, a1), pk(a2, a3));
            }
            cfence();

            // ---- L2: h2^T = W2^T @ h1^T
            bf16x8 h1f0 = *(const bf16x8*)(hw + hro0);
            bf16x8 h1f1 = *(const bf16x8*)(hw + hro0 + 32);
            f32x4 acc2[4];
            #pragma unroll
            for (int t = 0; t < 4; ++t) {
                f32x4 c2 = b2rv[t];
                c2 = MFMA16(w2f[t][0], h1f0, c2);
                acc2[t] = MFMA16(w2f[t][1], h1f1, c2);
            }
            cfence();
            // h2 overwrites h1 rows (in-order DS pipe; reads above precede)
            #pragma unroll
            for (int t = 0; t < 4; ++t) {
                float a0 = fmaxf(acc2[t][0], 0.0f), a1 = fmaxf(acc2[t][1], 0.0f);
                float a2 = fmaxf(acc2[t][2], 0.0f), a3 = fmaxf(acc2[t][3], 0.0f);
                *(int2*)(hw + nn * HS + t * 16 + q * 4) = make_int2(pk(a0, a1), pk(a2, a3));
            }
            cfence();

            // ---- L3: h3 = h2 @ W3
            bf16x8 h2f0 = *(const bf16x8*)(hw + hro0);
            bf16x8 h2f1 = *(const bf16x8*)(hw + hro0 + 32);
            f32x4 acc3 = {b3r, b3r, b3r, b3r};
            acc3 = MFMA16(h2f0, w3f[0], acc3);
            acc3 = MFMA16(h2f1, w3f[1], acc3);
            cfence();   // keep next sub's h1 writes behind these reads

            // ---- sigmoid + store: lane (q, nn<3), reg r -> out[pt][nn]
            float o0 = sigmoid_fast(acc3[0]);
            float o1 = sigmoid_fast(acc3[1]);
            float o2 = sigmoid_fast(acc3[2]);
            float o3 = sigmoid_fast(acc3[3]);
            if (nn < 3) {
                const float* dummy = ob;  (void)dummy;
                float* o = (float*)(ob + sub * 48 + oofs);
                o[0] = o0; o[3] = o1; o[6] = o2; o[9] = o3;
            }
        }
        cfence();   // next tile's xbuf writes stay behind this tile's reads
    }
}

extern "C" void kernel_launch(void* const* d_in, const int* in_sizes, int n_in,
                              void* d_out, int out_size, void* d_ws, size_t ws_size,
                              hipStream_t stream) {
    const float* pos = (const float*)d_in[0];
    const float* nrm = (const float*)d_in[1];
    const float* emb = (const float*)d_in[2];
    const float* W1  = (const float*)d_in[3];
    const float* b1  = (const float*)d_in[4];
    const float* W2  = (const float*)d_in[5];
    const float* b2  = (const float*)d_in[6];
    const float* W3  = (const float*)d_in[7];
    const float* b3  = (const float*)d_in[8];
    float* out = (float*)d_out;

    int n = in_sizes[0] / 3;      // 2,097,152
    int ntiles = n / 64;          // 32768
    int grid = 1024;              // 4096 waves -> exactly 8 tiles each
    nrad_mfma_kernel<<<grid, 256, 0, stream>>>(pos, nrm, emb, W1, b1, W2, b2,
                                               W3, b3, out, ntiles);
}

// Round 5
// 152.119 us; speedup vs baseline: 1.2969x; 1.0897x over previous
//
#include <hip/hip_runtime.h>
#include <cstdint>

// NeuralRadiance via bf16 MFMA (16x16x32), register-only inter-layer transforms.
//   L1 (transposed): h1^T = W1^T @ x^T   -- b1 folded as x[k=19]=1.0
//   L2 (transposed): h2^T = W2^T @ h1^T  -- b2 via MFMA C operand
//   L3 (normal)    : h3   = h2  @ W3     -- b3 via MFMA C operand
// Fragment facts (HW-verified per guide):
//   A-frag: lane holds A[m=lane&15][k=quad*8+j], 8 bf16
//   B-frag: lane holds B[k=quad*8+j][n=lane&15], 8 bf16
//   C/D   : lane reg r holds D[m=quad*4+r][n=lane&15], 4 f32
// Round 5: the C/D->frag transform is done IN REGISTERS with gfx950
// v_permlane32_swap_b32 + v_permlane16_swap_b32 (4 pairs, 8 ops) instead of
// an LDS round-trip. Derivation: pack P[t*2+h] = pk(acc[t][2h],acc[t][2h+1])
// (feat = t*16 + q*4 + 2h+{0,1}); target frag dword j' (k=8q+2j'+{0,1}) needs
// P[t=2F+(q>>1)][h=j'&1] from lane qq group: j'<2 -> qq=2q&3, j'>=2 -> (2q+1)&3.
// pl32 then pl16 on (P[4F+p], P[4F+2+p]) yields exactly (T_{j'=p}, T_{j'=p+2}).
// Only remaining LDS: x staging (4 b128 writes + 1 b128 read/sub).

typedef short  bf16x8 __attribute__((ext_vector_type(8)));
typedef float  f32x4  __attribute__((ext_vector_type(4)));

#define MFMA16(A, B, C) __builtin_amdgcn_mfma_f32_16x16x32_bf16((A), (B), (C), 0, 0, 0)

// guaranteed-HW packed cvt: 2 f32 -> dword of 2 bf16 (lo=a, hi=b), RNE
__device__ inline int pk(float a, float b) {
    int d;
    __asm__("v_cvt_pk_bf16_f32 %0, %1, %2" : "=v"(d) : "v"(a), "v"(b));
    return d;
}
// scalar fallback for cold weight staging
__device__ inline uint32_t f2b_u(float f) {
    union { float f; uint32_t u; } x; x.f = f;
    return (x.u + 0x7FFFu + ((x.u >> 16) & 1u)) >> 16;
}
__device__ inline short f2b(float f) { return (short)f2b_u(f); }

// gfx950 lane-transpose primitives (both operands read-write)
__device__ inline void pl32_swap(int& a, int& b) {
    __asm__ volatile("v_permlane32_swap_b32 %0, %1" : "+v"(a), "+v"(b));
}
__device__ inline void pl16_swap(int& a, int& b) {
    __asm__ volatile("v_permlane16_swap_b32 %0, %1" : "+v"(a), "+v"(b));
}

// compile-time ordering only (DS pipe is in-order per wave; validated r4)
__device__ inline void cfence() { __asm__ volatile("" ::: "memory"); }

__device__ inline float sigmoid_fast(float x) {
    float e = __expf(-x);
    return __builtin_amdgcn_rcpf(1.0f + e);
}

// C/D accs (4x f32x4) -> two frag halves (int4 of bf16 pairs), with relu.
__device__ inline void cd_to_frag(const f32x4 acc[4], int4& lo, int4& hi) {
    int P0 = pk(fmaxf(acc[0][0],0.f), fmaxf(acc[0][1],0.f));
    int P1 = pk(fmaxf(acc[0][2],0.f), fmaxf(acc[0][3],0.f));
    int P2 = pk(fmaxf(acc[1][0],0.f), fmaxf(acc[1][1],0.f));
    int P3 = pk(fmaxf(acc[1][2],0.f), fmaxf(acc[1][3],0.f));
    int P4 = pk(fmaxf(acc[2][0],0.f), fmaxf(acc[2][1],0.f));
    int P5 = pk(fmaxf(acc[2][2],0.f), fmaxf(acc[2][3],0.f));
    int P6 = pk(fmaxf(acc[3][0],0.f), fmaxf(acc[3][1],0.f));
    int P7 = pk(fmaxf(acc[3][2],0.f), fmaxf(acc[3][3],0.f));
    pl32_swap(P0, P2); pl16_swap(P0, P2);   // -> T0, T2
    pl32_swap(P1, P3); pl16_swap(P1, P3);   // -> T1, T3
    pl32_swap(P4, P6); pl16_swap(P4, P6);   // -> T4, T6
    pl32_swap(P5, P7); pl16_swap(P5, P7);   // -> T5, T7
    lo = make_int4(P0, P1, P2, P3);
    hi = make_int4(P4, P5, P6, P7);
}

__device__ inline bf16x8 as_frag(int4 v) {
    bf16x8 f; __builtin_memcpy(&f, &v, sizeof(f)); return f;
}

#define XS 40   // xbuf row stride in shorts (20 dwords; b128 at bank floor)

__global__ __launch_bounds__(256, 4) void nrad_mfma_kernel(
    const float* __restrict__ pos, const float* __restrict__ nrm,
    const float* __restrict__ emb,
    const float* __restrict__ W1, const float* __restrict__ b1,
    const float* __restrict__ W2, const float* __restrict__ b2,
    const float* __restrict__ W3, const float* __restrict__ b3,
    float* __restrict__ out, int ntiles)
{
    // Arena, two barrier-separated lifetimes:
    //  phase 1: w1t@0 (4KB) w2t@4096 (8KB) w3t@12288 (384B) b2s@12672 b3s@12928
    //  phase 2: xbuf = arena + wave*5120 (64 rows x XS shorts)
    __shared__ alignas(16) char arena[20480];
    short* w1t = (short*)arena;             // [n][k] stride 32: k<19=W1, k==19=b1
    short* w2t = (short*)(arena + 4096);    // [n][k] stride 64
    short* w3t = (short*)(arena + 12288);   // [c][k] stride 64
    float* b2s = (float*)(arena + 12672);
    float* b3s = (float*)(arena + 12928);

    const int tid  = threadIdx.x;
    const int wave = tid >> 6;
    const int lane = tid & 63;
    const int q    = lane >> 4;
    const int nn   = lane & 15;

    // ---- one-time: stage transposed bf16 weights into LDS
    for (int e = tid; e < 64 * 32; e += 256) {
        int n = e >> 5, k = e & 31;
        float v = (k < 19) ? W1[k * 64 + n] : (k == 19 ? b1[n] : 0.0f);
        w1t[n * 32 + k] = f2b(v);
    }
    for (int e = tid; e < 4096; e += 256) {
        int k = e >> 6, n = e & 63;
        w2t[n * 64 + k] = f2b(W2[e]);
    }
    for (int e = tid; e < 192; e += 256) {
        int k = e / 3, c = e - k * 3;
        w3t[c * 64 + k] = f2b(W3[e]);
    }
    for (int e = tid; e < 64; e += 256) b2s[e] = b2[e];
    if (tid < 4) b3s[tid] = (tid < 3) ? b3[tid] : 0.0f;
    __syncthreads();

    // ---- per-lane register fragments (persistent across tiles)
    bf16x8 w1f[4], w2f[4][2], w3f[2];
    #pragma unroll
    for (int t = 0; t < 4; ++t)
        w1f[t] = *(const bf16x8*)(w1t + (t * 16 + nn) * 32 + q * 8);
    #pragma unroll
    for (int t = 0; t < 4; ++t)
        #pragma unroll
        for (int ks = 0; ks < 2; ++ks)
            w2f[t][ks] = *(const bf16x8*)(w2t + (t * 16 + nn) * 64 + ks * 32 + q * 8);
    {
        int c3 = (nn < 3) ? nn : 0;
        w3f[0] = *(const bf16x8*)(w3t + c3 * 64 + q * 8);
        w3f[1] = *(const bf16x8*)(w3t + c3 * 64 + 32 + q * 8);
    }
    f32x4 b2rv[4];
    #pragma unroll
    for (int t = 0; t < 4; ++t)
        b2rv[t] = *(const f32x4*)(b2s + t * 16 + q * 4);
    const float b3r = (nn < 3) ? b3s[nn] : 0.0f;
    __syncthreads();   // weights consumed into regs; arena now reusable

    short* xw = (short*)(arena + wave * 5120);   // row stride XS shorts

    const int xro  = nn * XS + q * 8;    // + sub*16*XS : L1 B-frag read
    const int oofs = q * 12 + nn;        // out: (q*4+r)*3+nn, r via stride 3

    const int wave_gid = blockIdx.x * 4 + wave;
    const int nwaves   = gridDim.x * 4;
    const float4* emb4 = (const float4*)emb;

    for (int tile = wave_gid; tile < ntiles; tile += nwaves) {
        const int base = tile * 64;
        const int i    = base + lane;

        // ---- load + hash + gather this lane's point
        const float* pp = pos + 3 * i;
        const float* np = nrm + 3 * i;
        float p0 = pp[0], p1 = pp[1], p2 = pp[2];
        float n0 = np[0], n1 = np[1], n2 = np[2];
        int s0 = (int)(p0 * 8.0f), s1 = (int)(p1 * 8.0f), s2 = (int)(p2 * 8.0f);
        uint32_t h = ((uint32_t)s0 * 73856093u) ^ ((uint32_t)s1 * 19349663u) ^
                     ((uint32_t)s2 * 83492791u);
        uint32_t idx = h & 32767u;
        float4 f0 = emb4[idx*4+0], f1 = emb4[idx*4+1];
        float4 f2 = emb4[idx*4+2], f3 = emb4[idx*4+3];

        // ---- pack into xbuf row = lane (k-major, 32 shorts + 8 pad)
        int4 A = make_int4(pk(f0.x, f0.y), pk(f0.z, f0.w), pk(f1.x, f1.y), pk(f1.z, f1.w));
        int4 B = make_int4(pk(f2.x, f2.y), pk(f2.z, f2.w), pk(f3.x, f3.y), pk(f3.z, f3.w));
        int4 C = make_int4(pk(n0, n1), pk(n2, 1.0f), 0, 0);  // k=19 -> 1.0 (bias row)
        int4 D = make_int4(0, 0, 0, 0);
        int4* xr = (int4*)(xw + lane * XS);
        xr[0] = A; xr[1] = B; xr[2] = C; xr[3] = D;
        cfence();

        const float* ob = out + (size_t)base * 3;

        #pragma unroll
        for (int sub = 0; sub < 4; ++sub) {
            // ---- L1: h1^T = W1^T @ x^T (the only LDS read per sub)
            bf16x8 xf = *(const bf16x8*)(xw + sub * 16 * XS + xro);
            f32x4 acc1[4];
            #pragma unroll
            for (int t = 0; t < 4; ++t) {
                f32x4 z = {0.0f, 0.0f, 0.0f, 0.0f};
                acc1[t] = MFMA16(w1f[t], xf, z);
            }

            // ---- relu + pack + register transpose -> h1^T B-frags
            int4 h1lo, h1hi;
            cd_to_frag(acc1, h1lo, h1hi);
            bf16x8 h1f0 = as_frag(h1lo), h1f1 = as_frag(h1hi);

            // ---- L2: h2^T = W2^T @ h1^T
            f32x4 acc2[4];
            #pragma unroll
            for (int t = 0; t < 4; ++t) {
                f32x4 c2 = MFMA16(w2f[t][0], h1f0, b2rv[t]);
                acc2[t]  = MFMA16(w2f[t][1], h1f1, c2);
            }

            // ---- relu + pack + register transpose -> h2 A-frags
            int4 h2lo, h2hi;
            cd_to_frag(acc2, h2lo, h2hi);
            bf16x8 h2f0 = as_frag(h2lo), h2f1 = as_frag(h2hi);

            // ---- L3: h3 = h2 @ W3
            f32x4 cb = {b3r, b3r, b3r, b3r};
            f32x4 c3a = MFMA16(h2f0, w3f[0], cb);
            f32x4 acc3 = MFMA16(h2f1, w3f[1], c3a);

            // ---- sigmoid + store: lane (q, nn<3), reg r -> out[pt][nn]
            float o0 = sigmoid_fast(acc3[0]);
            float o1 = sigmoid_fast(acc3[1]);
            float o2 = sigmoid_fast(acc3[2]);
            float o3 = sigmoid_fast(acc3[3]);
            if (nn < 3) {
                float* o = (float*)(ob + sub * 48 + oofs);
                o[0] = o0; o[3] = o1; o[6] = o2; o[9] = o3;
            }
        }
        cfence();   // next tile's xbuf writes stay behind this tile's reads
    }
}

extern "C" void kernel_launch(void* const* d_in, const int* in_sizes, int n_in,
                              void* d_out, int out_size, void* d_ws, size_t ws_size,
                              hipStream_t stream) {
    const float* pos = (const float*)d_in[0];
    const float* nrm = (const float*)d_in[1];
    const float* emb = (const float*)d_in[2];
    const float* W1  = (const float*)d_in[3];
    const float* b1  = (const float*)d_in[4];
    const float* W2  = (const float*)d_in[5];
    const float* b2  = (const float*)d_in[6];
    const float* W3  = (const float*)d_in[7];
    const float* b3  = (const float*)d_in[8];
    float* out = (float*)d_out;

    int n = in_sizes[0] / 3;      // 2,097,152
    int ntiles = n / 64;          // 32768
    int grid = 1024;              // 4096 waves -> exactly 8 tiles each; 4 blocks/CU
    nrad_mfma_kernel<<<grid, 256, 0, stream>>>(pos, nrm, emb, W1, b1, W2, b2,
                                               W3, b3, out, ntiles);
}